// Round 1
// baseline (7438.965 us; speedup 1.0000x reference)
//
#include <hip/hip_runtime.h>
#include <cmath>

#define VOCABN 32000
#define EE 128
#define HH 256
#define H3 768
#define HOPSN 3
#define HEADSN 4
#define NB 32
#define TMN 50
#define WLENN 20
#define TQN 20

// workspace offsets (in floats)
#define OFF_WIHT_I 0
#define OFF_WHHT_I (OFF_WIHT_I + EE*H3)
#define OFF_WIHT_Q (OFF_WHHT_I + HH*H3)
#define OFF_WHHT_Q (OFF_WIHT_Q + EE*H3)
#define OFF_MEM    (OFF_WHHT_Q + HH*H3)
#define OFF_Q      (OFF_MEM + NB*TMN*HH)
#define OFF_OK     (OFF_Q + NB*HH)
#define OFF_WB     (OFF_OK + NB*HH)
#define OFF_REP    (OFF_WB + NB*HOPSN*HH)
#define OFF_G2     (OFF_REP + NB*HEADSN*HH)
#define OFF_REAS   (OFF_G2 + NB*9*H3)

__device__ __forceinline__ float sigm(float x) { return 1.f / (1.f + expf(-x)); }

// ---------------- K1: transpose GRU weights to [k][o] layout for coalesced matvec ----------------
__global__ void k_transpose(const float* __restrict__ qWih, const float* __restrict__ qWhh,
                            const float* __restrict__ iWih, const float* __restrict__ iWhh,
                            float* __restrict__ ws)
{
    float* WihT_i = ws + OFF_WIHT_I;
    float* WhhT_i = ws + OFF_WHHT_I;
    float* WihT_q = ws + OFF_WIHT_Q;
    float* WhhT_q = ws + OFF_WHHT_Q;
    const int tid = blockIdx.x * blockDim.x + threadIdx.x;
    const int nt  = gridDim.x * blockDim.x;
    for (int idx = tid; idx < H3 * EE; idx += nt) {
        int j = idx / EE, e = idx % EE;
        WihT_i[e * H3 + j] = iWih[idx];
        WihT_q[e * H3 + j] = qWih[idx];
    }
    for (int idx = tid; idx < H3 * HH; idx += nt) {
        int j = idx / HH, k = idx % HH;
        WhhT_i[k * H3 + j] = iWhh[idx];
        WhhT_q[k * H3 + j] = qWhh[idx];
    }
}

// ---------------- K2: recurrent GRUs. blocks 0..49 = input memory slots, 50..81 = question rows --
__global__ __launch_bounds__(768) void k_gru(const int* __restrict__ stories, const int* __restrict__ questions,
                                             const float* __restrict__ emb,
                                             const float* __restrict__ ibih, const float* __restrict__ ibhh,
                                             const float* __restrict__ qbih, const float* __restrict__ qbhh,
                                             float* __restrict__ ws)
{
    __shared__ float hs[HH];
    __shared__ float xs[EE];
    __shared__ float ab[H3];
    __shared__ float bb[H3];
    const int j = threadIdx.x;
    const int blk = blockIdx.x;
    const bool isq = blk >= TMN;
    const float* __restrict__ WihT = ws + (isq ? OFF_WIHT_Q : OFF_WIHT_I);
    const float* __restrict__ WhhT = ws + (isq ? OFF_WHHT_Q : OFF_WHHT_I);
    const float bihj = (isq ? qbih : ibih)[j];
    const float bhhj = (isq ? qbhh : ibhh)[j];
    float* __restrict__ memv = ws + OFF_MEM;
    float* __restrict__ qv   = ws + OFF_Q;
    if (j < HH) hs[j] = 0.f;
    const int nOuter = isq ? 1 : NB;
    const int qn = blk - TMN;
    __syncthreads();
    for (int n = 0; n < nOuter; ++n) {
        for (int t = 0; t < WLENN; ++t) {   // WLEN == TQ == 20
            const int tok = isq ? questions[qn * TQN + t] : stories[(n * TMN + blk) * WLENN + t];
            if (j < EE) xs[j] = emb[tok * EE + j];
            __syncthreads();
            // gi = x @ Wih.T  (on-the-fly)
            float a0 = 0.f, a1 = 0.f, a2 = 0.f, a3 = 0.f;
            #pragma unroll 8
            for (int e = 0; e < EE; e += 4) {
                const float4 xv = *reinterpret_cast<const float4*>(&xs[e]);
                a0 = fmaf(xv.x, WihT[(e + 0) * H3 + j], a0);
                a1 = fmaf(xv.y, WihT[(e + 1) * H3 + j], a1);
                a2 = fmaf(xv.z, WihT[(e + 2) * H3 + j], a2);
                a3 = fmaf(xv.w, WihT[(e + 3) * H3 + j], a3);
            }
            // gh = h @ Whh.T
            float b0 = 0.f, b1 = 0.f, b2 = 0.f, b3 = 0.f;
            #pragma unroll 8
            for (int k = 0; k < HH; k += 4) {
                const float4 hv = *reinterpret_cast<const float4*>(&hs[k]);
                b0 = fmaf(hv.x, WhhT[(k + 0) * H3 + j], b0);
                b1 = fmaf(hv.y, WhhT[(k + 1) * H3 + j], b1);
                b2 = fmaf(hv.z, WhhT[(k + 2) * H3 + j], b2);
                b3 = fmaf(hv.w, WhhT[(k + 3) * H3 + j], b3);
            }
            ab[j] = bihj + ((a0 + a1) + (a2 + a3));
            bb[j] = bhhj + ((b0 + b1) + (b2 + b3));
            __syncthreads();
            if (j < HH) {
                const float r  = sigm(ab[j] + bb[j]);
                const float z  = sigm(ab[HH + j] + bb[HH + j]);
                const float nn = tanhf(ab[2 * HH + j] + r * bb[2 * HH + j]);
                hs[j] = (1.f - z) * nn + z * hs[j];
            }
            __syncthreads();
        }
        if (!isq && j < HH) memv[(n * TMN + blk) * HH + j] = hs[j];
    }
    if (isq && j < HH) qv[qn * HH + j] = hs[j];
}

// ---------------- K3: ft(x) = relu(relu(x@W1.T+b1)@W2.T+b2), one block per row ----------------
__global__ __launch_bounds__(256) void k_ft(const float* __restrict__ src, float* __restrict__ dst,
                                            const float* __restrict__ W1, const float* __restrict__ b1,
                                            const float* __restrict__ W2, const float* __restrict__ b2)
{
    __shared__ float xr[HH];
    __shared__ float y1[HH];
    const int n = blockIdx.x, j = threadIdx.x;
    xr[j] = src[n * HH + j];
    __syncthreads();
    float acc = b1[j];
    const float4* w1 = reinterpret_cast<const float4*>(W1 + j * HH);
    #pragma unroll 4
    for (int k4 = 0; k4 < HH / 4; ++k4) {
        const float4 w = w1[k4];
        const float4 x = *reinterpret_cast<const float4*>(&xr[k4 * 4]);
        acc = fmaf(x.x, w.x, fmaf(x.y, w.y, fmaf(x.z, w.z, fmaf(x.w, w.w, acc))));
    }
    y1[j] = fmaxf(acc, 0.f);
    __syncthreads();
    acc = b2[j];
    const float4* w2 = reinterpret_cast<const float4*>(W2 + j * HH);
    #pragma unroll 4
    for (int k4 = 0; k4 < HH / 4; ++k4) {
        const float4 w = w2[k4];
        const float4 x = *reinterpret_cast<const float4*>(&y1[k4 * 4]);
        acc = fmaf(x.x, w.x, fmaf(x.y, w.y, fmaf(x.z, w.z, fmaf(x.w, w.w, acc))));
    }
    dst[n * HH + j] = fmaxf(acc, 0.f);
}

// ---------------- K4: attention scores + rep for one hop; block = (n, head) ----------------
__global__ __launch_bounds__(256) void k_attn(const float* __restrict__ Wm, float* __restrict__ ws, int hp)
{
    __shared__ float mem_s[TMN][HH];   // 51.2 KB
    __shared__ float ok_s[HH];
    __shared__ float wred[4][TMN];
    __shared__ float sc[TMN];
    const int n = blockIdx.x / HEADSN, hh = blockIdx.x % HEADSN;
    const int e = threadIdx.x;
    const float* __restrict__ memory = ws + OFF_MEM + n * TMN * HH;
    for (int idx = e; idx < TMN * HH; idx += HH)
        (&mem_s[0][0])[idx] = memory[idx];
    ok_s[e] = (ws + OFF_OK)[n * HH + e];
    __syncthreads();

    float p[TMN];
    #pragma unroll
    for (int t = 0; t < TMN; ++t) p[t] = 0.f;
    const float4* wrow = reinterpret_cast<const float4*>(Wm + ((size_t)(hp * HEADSN + hh) * HH + e) * HH);
    for (int d4 = 0; d4 < HH / 4; ++d4) {
        const float4 w = wrow[d4];
        #pragma unroll
        for (int t = 0; t < TMN; ++t) {
            const float4 m = *reinterpret_cast<const float4*>(&mem_s[t][d4 * 4]);
            p[t] = fmaf(m.x, w.x, fmaf(m.y, w.y, fmaf(m.z, w.z, fmaf(m.w, w.w, p[t]))));
        }
    }
    const float okv = ok_s[e];
    const int lane = e & 63, wv = e >> 6;
    #pragma unroll
    for (int t = 0; t < TMN; ++t) {
        float v = tanhf(p[t]) * okv;
        #pragma unroll
        for (int off = 32; off > 0; off >>= 1) v += __shfl_xor(v, off);
        if (lane == 0) wred[wv][t] = v;
    }
    __syncthreads();
    if (e < TMN) sc[e] = wred[0][e] + wred[1][e] + wred[2][e] + wred[3][e];
    __syncthreads();
    if (e == 0) {
        float mx = sc[0];
        for (int t = 1; t < TMN; ++t) mx = fmaxf(mx, sc[t]);
        float sum = 0.f;
        for (int t = 0; t < TMN; ++t) { const float ex = expf(sc[t] - mx); sc[t] = ex; sum += ex; }
        const float inv = 1.f / sum;
        for (int t = 0; t < TMN; ++t) sc[t] *= inv;
    }
    __syncthreads();
    float r = 0.f;
    #pragma unroll
    for (int t = 0; t < TMN; ++t) r = fmaf(sc[t], mem_s[t][e], r);
    (ws + OFF_REP)[(n * HEADSN + hh) * HH + e] = r;
}

// ---------------- K5: buf = rep_flat @ Wo_w.T + Wo_b; wb[n][hp]=buf; o_k = ft(buf) -------------
__global__ __launch_bounds__(256) void k_buf(const float* __restrict__ Wo_w, const float* __restrict__ Wo_b,
                                             const float* __restrict__ W1, const float* __restrict__ b1,
                                             const float* __restrict__ W2, const float* __restrict__ b2,
                                             float* __restrict__ ws, int hp)
{
    __shared__ float repf[HEADSN * HH];  // 1024
    __shared__ float bufs[HH];
    __shared__ float y1[HH];
    const int n = blockIdx.x, j = threadIdx.x;
    const float* __restrict__ rep = ws + OFF_REP + n * HEADSN * HH;
    for (int idx = j; idx < HEADSN * HH; idx += HH) repf[idx] = rep[idx];
    __syncthreads();
    float acc = Wo_b[hp * HH + j];
    const float4* wrow = reinterpret_cast<const float4*>(Wo_w + ((size_t)hp * HH + j) * (HEADSN * HH));
    #pragma unroll 4
    for (int c4 = 0; c4 < HEADSN * HH / 4; ++c4) {
        const float4 w = wrow[c4];
        const float4 x = *reinterpret_cast<const float4*>(&repf[c4 * 4]);
        acc = fmaf(x.x, w.x, fmaf(x.y, w.y, fmaf(x.z, w.z, fmaf(x.w, w.w, acc))));
    }
    (ws + OFF_WB)[(n * HOPSN + hp) * HH + j] = acc;
    bufs[j] = acc;
    __syncthreads();
    float a1 = b1[j];
    const float4* w1 = reinterpret_cast<const float4*>(W1 + j * HH);
    #pragma unroll 4
    for (int k4 = 0; k4 < HH / 4; ++k4) {
        const float4 w = w1[k4];
        const float4 x = *reinterpret_cast<const float4*>(&bufs[k4 * 4]);
        a1 = fmaf(x.x, w.x, fmaf(x.y, w.y, fmaf(x.z, w.z, fmaf(x.w, w.w, a1))));
    }
    y1[j] = fmaxf(a1, 0.f);
    __syncthreads();
    float a2 = b2[j];
    const float4* w2 = reinterpret_cast<const float4*>(W2 + j * HH);
    #pragma unroll 4
    for (int k4 = 0; k4 < HH / 4; ++k4) {
        const float4 w = w2[k4];
        const float4 x = *reinterpret_cast<const float4*>(&y1[k4 * 4]);
        a2 = fmaf(x.x, w.x, fmaf(x.y, w.y, fmaf(x.z, w.z, fmaf(x.w, w.w, a2))));
    }
    (ws + OFF_OK)[n * HH + j] = fmaxf(a2, 0.f);
}

// ---------------- K6: relation MLP for one (n, pair); writes g2 ----------------
__global__ __launch_bounds__(768) void k_rm(const float* __restrict__ gW1, const float* __restrict__ gb1,
                                            const float* __restrict__ gW2, const float* __restrict__ gb2,
                                            float* __restrict__ ws)
{
    __shared__ float comb[H3];
    __shared__ float y1[H3];
    const int n = blockIdx.x / 9, p = blockIdx.x % 9;
    const int ii = p / 3, jj = p % 3;
    const int tid = threadIdx.x;
    const float* __restrict__ wb = ws + OFF_WB + n * HOPSN * HH;
    const float* __restrict__ qv = ws + OFF_Q + n * HH;
    if (tid < HH)           comb[tid] = wb[jj * HH + tid];            // left  = wb[:, j]
    else if (tid < 2 * HH)  comb[tid] = wb[ii * HH + (tid - HH)];     // right = wb[:, i]
    else                    comb[tid] = qv[tid - 2 * HH];             // q
    __syncthreads();
    float acc = gb1[tid];
    const float4* w1 = reinterpret_cast<const float4*>(gW1 + (size_t)tid * H3);
    #pragma unroll 4
    for (int c4 = 0; c4 < H3 / 4; ++c4) {
        const float4 w = w1[c4];
        const float4 x = *reinterpret_cast<const float4*>(&comb[c4 * 4]);
        acc = fmaf(x.x, w.x, fmaf(x.y, w.y, fmaf(x.z, w.z, fmaf(x.w, w.w, acc))));
    }
    y1[tid] = fmaxf(acc, 0.f);
    __syncthreads();
    acc = gb2[tid];
    const float4* w2 = reinterpret_cast<const float4*>(gW2 + (size_t)tid * H3);
    #pragma unroll 4
    for (int c4 = 0; c4 < H3 / 4; ++c4) {
        const float4 w = w2[c4];
        const float4 x = *reinterpret_cast<const float4*>(&y1[c4 * 4]);
        acc = fmaf(x.x, w.x, fmaf(x.y, w.y, fmaf(x.z, w.z, fmaf(x.w, w.w, acc))));
    }
    (ws + OFF_G2)[((size_t)n * 9 + p) * H3 + tid] = fmaxf(acc, 0.f);
}

// ---------------- K7: reasoning = sum over 9 pairs ----------------
__global__ void k_reduce(float* __restrict__ ws)
{
    const int idx = blockIdx.x * blockDim.x + threadIdx.x;
    if (idx >= NB * H3) return;
    const int n = idx / H3, d = idx % H3;
    const float* __restrict__ g2 = ws + OFF_G2 + (size_t)n * 9 * H3 + d;
    float s = 0.f;
    #pragma unroll
    for (int p = 0; p < 9; ++p) s += g2[p * H3];
    (ws + OFF_REAS)[idx] = s;
}

// ---------------- K8: out = reasoning @ V_w.T  (stage all reasoning in LDS) ----------------
__global__ __launch_bounds__(256) void k_out(const float* __restrict__ V_w, const float* __restrict__ ws,
                                             float* __restrict__ out)
{
    __shared__ float rs[NB * H3];   // 98.3 KB (gfx950 allows 160 KB)
    const int v = blockIdx.x * 256 + threadIdx.x;
    for (int idx = threadIdx.x; idx < NB * H3; idx += 256) rs[idx] = (ws + OFF_REAS)[idx];
    __syncthreads();
    float acc[NB];
    #pragma unroll
    for (int nn = 0; nn < NB; ++nn) acc[nn] = 0.f;
    const float4* vw = reinterpret_cast<const float4*>(V_w + (size_t)v * H3);
    for (int d4 = 0; d4 < H3 / 4; ++d4) {
        const float4 w = vw[d4];
        #pragma unroll
        for (int nn = 0; nn < NB; ++nn) {
            const float4 r = *reinterpret_cast<const float4*>(&rs[nn * H3 + d4 * 4]);
            acc[nn] = fmaf(r.x, w.x, fmaf(r.y, w.y, fmaf(r.z, w.z, fmaf(r.w, w.w, acc[nn]))));
        }
    }
    #pragma unroll
    for (int nn = 0; nn < NB; ++nn) out[(size_t)nn * VOCABN + v] = acc[nn];
}

extern "C" void kernel_launch(void* const* d_in, const int* in_sizes, int n_in,
                              void* d_out, int out_size, void* d_ws, size_t ws_size,
                              hipStream_t stream)
{
    const int*   stories   = (const int*)d_in[0];
    const int*   questions = (const int*)d_in[1];
    const float* emb   = (const float*)d_in[2];
    const float* qWih  = (const float*)d_in[3];
    const float* qWhh  = (const float*)d_in[4];
    const float* qbih  = (const float*)d_in[5];
    const float* qbhh  = (const float*)d_in[6];
    const float* iWih  = (const float*)d_in[7];
    const float* iWhh  = (const float*)d_in[8];
    const float* ibih  = (const float*)d_in[9];
    const float* ibhh  = (const float*)d_in[10];
    const float* Wm    = (const float*)d_in[11];
    const float* Wo_w  = (const float*)d_in[12];
    const float* Wo_b  = (const float*)d_in[13];
    const float* ftW1  = (const float*)d_in[14];
    const float* ftb1  = (const float*)d_in[15];
    const float* ftW2  = (const float*)d_in[16];
    const float* ftb2  = (const float*)d_in[17];
    const float* gW1   = (const float*)d_in[18];
    const float* gb1   = (const float*)d_in[19];
    const float* gW2   = (const float*)d_in[20];
    const float* gb2   = (const float*)d_in[21];
    const float* V_w   = (const float*)d_in[22];
    float* ws  = (float*)d_ws;
    float* out = (float*)d_out;

    hipLaunchKernelGGL(k_transpose, dim3(128), dim3(256), 0, stream, qWih, qWhh, iWih, iWhh, ws);
    hipLaunchKernelGGL(k_gru, dim3(TMN + NB), dim3(H3), 0, stream,
                       stories, questions, emb, ibih, ibhh, qbih, qbhh, ws);
    hipLaunchKernelGGL(k_ft, dim3(NB), dim3(HH), 0, stream, ws + OFF_Q, ws + OFF_OK, ftW1, ftb1, ftW2, ftb2);
    for (int hp = 0; hp < HOPSN; ++hp) {
        hipLaunchKernelGGL(k_attn, dim3(NB * HEADSN), dim3(HH), 0, stream, Wm, ws, hp);
        hipLaunchKernelGGL(k_buf, dim3(NB), dim3(HH), 0, stream, Wo_w, Wo_b, ftW1, ftb1, ftW2, ftb2, ws, hp);
    }
    hipLaunchKernelGGL(k_rm, dim3(NB * 9), dim3(H3), 0, stream, gW1, gb1, gW2, gb2, ws);
    hipLaunchKernelGGL(k_reduce, dim3((NB * H3 + 255) / 256), dim3(256), 0, stream, ws);
    hipLaunchKernelGGL(k_out, dim3(VOCABN / 256), dim3(256), 0, stream, V_w, ws, out);
}